// Round 1
// baseline (216.168 us; speedup 1.0000x reference)
//
#include <hip/hip_runtime.h>
#include <math.h>

// MoE router: B=4, T=4096, D=2048, E=64, K=2
//   logits = x @ gate_w^T  -> [16384, 64]
//   top-2 -> softmax over the 2 scores
// Outputs concatenated flat: weights [16384*2] f32, then indices [16384*2]
// written as float values (harness reads non-bf16 outputs through float*).

#define NTOK 16384
#define DDIM 2048
#define NEXP 64
#define TOK_PER_BLK 64
#define NWAVE 8
#define DCHUNK 256   // D slice per wave: 8 * 256 = 2048

__global__ __launch_bounds__(512) void moe_router_kernel(
    const float* __restrict__ x,      // [NTOK, DDIM]
    const float* __restrict__ gw,     // [NEXP, DDIM]
    float* __restrict__ out)          // [2*NTOK*2]
{
    // [wave][expert][token] partial logits: 8*64*64*4 = 128 KiB
    __shared__ float red[NWAVE][NEXP][TOK_PER_BLK];

    const int tid  = threadIdx.x;
    const int lane = tid & 63;
    const int wav  = __builtin_amdgcn_readfirstlane(tid >> 6); // wave-uniform SGPR
    const int tok0 = blockIdx.x * TOK_PER_BLK;
    const int token = tok0 + lane;
    const int dbase = wav * DCHUNK;

    const float* xrow = x + (size_t)token * DDIM + dbase;

    float acc[NEXP];
#pragma unroll
    for (int e = 0; e < NEXP; ++e) acc[e] = 0.f;

    // Main loop: 8 sub-chunks of 32 floats; x in registers, W rows wave-uniform.
    for (int sc = 0; sc < DCHUNK; sc += 32) {
        float4 xv[8];
#pragma unroll
        for (int j = 0; j < 8; ++j)
            xv[j] = *reinterpret_cast<const float4*>(xrow + sc + j * 4);

#pragma unroll 2
        for (int e = 0; e < NEXP; ++e) {
            const float4* wrow =
                reinterpret_cast<const float4*>(gw + (size_t)e * DDIM + dbase + sc);
            float s = acc[e];
#pragma unroll
            for (int j = 0; j < 8; ++j) {
                float4 wv = wrow[j];
                s += xv[j].x * wv.x;
                s += xv[j].y * wv.y;
                s += xv[j].z * wv.z;
                s += xv[j].w * wv.w;
            }
            acc[e] = s;
        }
    }

    // Write per-wave partials: lanes consecutive -> conflict-free ds_write
#pragma unroll
    for (int e = 0; e < NEXP; ++e) red[wav][e][lane] = acc[e];
    __syncthreads();

    // Reduce 8 -> 1 : 4096 (e,t) slots, 512 threads, 8 slots each (disjoint)
#pragma unroll
    for (int k = 0; k < 8; ++k) {
        int q = tid + k * 512;
        int t = q & 63;
        int e = q >> 6;
        float s = red[0][e][t];
#pragma unroll
        for (int wv = 1; wv < NWAVE; ++wv) s += red[wv][e][t];
        red[0][e][t] = s;   // owner-only slot: no cross-thread hazard
    }
    __syncthreads();

    // Top-2 + softmax: 64 lanes, lane t scans red[0][e][t] (conflict-free)
    if (tid < TOK_PER_BLK) {
        const int t = tid;
        float m1 = -INFINITY, m2 = -INFINITY;
        int i1 = 0, i2 = 0;
        for (int e = 0; e < NEXP; ++e) {
            float v = red[0][e][t];
            if (v > m1) {            // strict '>' keeps lowest index on ties (matches lax.top_k)
                m2 = m1; i2 = i1;
                m1 = v;  i1 = e;
            } else if (v > m2) {
                m2 = v;  i2 = e;
            }
        }
        float e2 = expf(m2 - m1);    // softmax([m1,m2]) with max subtracted
        float denom = 1.f + e2;
        float w1 = 1.f / denom;
        float w2 = e2 / denom;

        const int gt = tok0 + t;
        out[gt * 2 + 0] = w1;
        out[gt * 2 + 1] = w2;
        out[NTOK * 2 + gt * 2 + 0] = (float)i1;
        out[NTOK * 2 + gt * 2 + 1] = (float)i2;
    }
}

extern "C" void kernel_launch(void* const* d_in, const int* in_sizes, int n_in,
                              void* d_out, int out_size, void* d_ws, size_t ws_size,
                              hipStream_t stream) {
    const float* x  = (const float*)d_in[0];   // [4,4096,2048] f32
    const float* gw = (const float*)d_in[1];   // [64,2048] f32
    float* out = (float*)d_out;                // weights then indices, flat

    dim3 grid(NTOK / TOK_PER_BLK);  // 256 blocks
    dim3 block(512);                // 8 waves
    moe_router_kernel<<<grid, block, 0, stream>>>(x, gw, out);
}